// Round 11
// baseline (139.063 us; speedup 1.0000x reference)
//
#include <hip/hip_runtime.h>

#define EMB_D 128
#define SLOT_CAP 96      // max stored edges/slot; claimed-row deg ~Poisson(24), P(>96)~0
#define FILL_THREADS 256
#define EPT 8            // edges per thread per grid-stride iteration

typedef float f32x4 __attribute__((ext_vector_type(4)));

// ---------- Pass 1: claim needed nodes; slot map + inverse map + bitmap. ----------
__global__ void claim_kernel(const int* __restrict__ user_idx,
                             const int* __restrict__ item_idx,
                             int* __restrict__ node_map,
                             int* __restrict__ slot2node,
                             unsigned* __restrict__ bitmap,
                             int B, int U) {
    int t = blockIdx.x * blockDim.x + threadIdx.x;
    if (t >= 2 * B) return;
    int node = (t < B) ? user_idx[t] : (U + item_idx[t - B]);
    int old = atomicCAS(&node_map[node], 0, t + 1);
    if (old == 0) slot2node[t] = node;        // winner's slot -> node
    atomicOr(&bitmap[node >> 5], 1u << (node & 31));
}

__device__ __forceinline__ void slow_place_cv(int slot, int c, float v,
        float* __restrict__ comp,
        const float* __restrict__ user_emb, const float* __restrict__ item_emb,
        int U) {
    // ~never (deg > SLOT_CAP): exact fallback, comp pre-zeroed
    const float* src = (c < U) ? (user_emb + (size_t)c * EMB_D)
                               : (item_emb + (size_t)(c - U) * EMB_D);
    float* dst = comp + (size_t)slot * EMB_D;
    for (int i = 0; i < EMB_D; ++i) atomicAdd(dst + i, v * src[i]);
}

// ---------- Pass 2: persistent-block LDS-bitmap filter + bucketing. ----------
__global__ void __launch_bounds__(FILL_THREADS)
fill3_kernel(const float* __restrict__ user_emb,
             const float* __restrict__ item_emb,
             const float* __restrict__ vals,
             const int* __restrict__ rows,
             const int* __restrict__ cols,
             const int* __restrict__ node_map,
             const unsigned* __restrict__ bitmap, int nwords,
             int* __restrict__ deg,
             int2* __restrict__ edge_buf,
             float* __restrict__ comp,
             long long nnz, int U) {
    extern __shared__ unsigned lbm[];
    const int tid = threadIdx.x;
    for (int i = tid; i < nwords; i += FILL_THREADS) lbm[i] = bitmap[i];
    __syncthreads();

    const long long stride = (long long)gridDim.x * FILL_THREADS * EPT;
    for (long long blk = (long long)blockIdx.x * FILL_THREADS * EPT;
         blk < nnz; blk += stride) {
        long long e0 = blk + (long long)tid * EPT;
        if (e0 + EPT <= nnz) {
            // 8 consecutive edges: 2xint4 rows, 2xint4 cols, 2xfloat4 vals
            int4  ra = *(const int4*)(rows + e0);
            int4  rb = *(const int4*)(rows + e0 + 4);
            int4  ca = *(const int4*)(cols + e0);
            int4  cb = *(const int4*)(cols + e0 + 4);
            float4 va = *(const float4*)(vals + e0);
            float4 vb = *(const float4*)(vals + e0 + 4);
            int   r8[EPT] = {ra.x, ra.y, ra.z, ra.w, rb.x, rb.y, rb.z, rb.w};
            int   c8[EPT] = {ca.x, ca.y, ca.z, ca.w, cb.x, cb.y, cb.z, cb.w};
            float v8[EPT] = {va.x, va.y, va.z, va.w, vb.x, vb.y, vb.z, vb.w};
#pragma unroll
            for (int j = 0; j < EPT; ++j) {
                if ((lbm[r8[j] >> 5] >> (r8[j] & 31)) & 1u) {   // ~11.5%
                    int slot = node_map[r8[j]] - 1;
                    int pos = atomicAdd(&deg[slot], 1);
                    if (pos < SLOT_CAP)
                        edge_buf[(size_t)slot * SLOT_CAP + pos] =
                            make_int2(c8[j], __float_as_int(v8[j]));
                    else
                        slow_place_cv(slot, c8[j], v8[j], comp,
                                      user_emb, item_emb, U);
                }
            }
        } else {
            for (long long e = e0; e < nnz; ++e) {
                int r = rows[e];
                if ((lbm[r >> 5] >> (r & 31)) & 1u) {
                    int slot = node_map[r] - 1;
                    int c = cols[e];
                    float v = vals[e];
                    int pos = atomicAdd(&deg[slot], 1);
                    if (pos < SLOT_CAP)
                        edge_buf[(size_t)slot * SLOT_CAP + pos] =
                            make_int2(c, __float_as_int(v));
                    else
                        slow_place_cv(slot, c, v, comp, user_emb, item_emb, U);
                }
            }
        }
    }
}

__device__ __forceinline__ void fma4(float4& acc, float v, const float4& val) {
    acc.x = fmaf(v, val.x, acc.x);
    acc.y = fmaf(v, val.y, acc.y);
    acc.z = fmaf(v, val.z, acc.z);
    acc.w = fmaf(v, val.w, acc.w);
}

// ---------- Pass 3: one wave per slot; writes f = e0 + e1 into comp. ----------
__global__ void __launch_bounds__(256)
gather_kernel(const float* __restrict__ user_emb,
              const float* __restrict__ item_emb,
              const int2* __restrict__ edge_buf,
              const int* __restrict__ deg,
              const int* __restrict__ slot2node,
              float* __restrict__ comp,
              int nslots, int U) {
    int wid  = (blockIdx.x * blockDim.x + threadIdx.x) >> 6;
    int lane = threadIdx.x & 63;
    if (wid >= nslots) return;
    int d = deg[wid];
    bool ovf = (d > SLOT_CAP);
    int dc = ovf ? SLOT_CAP : d;
    const int2* eb = edge_buf + (size_t)wid * SLOT_CAP;
    const int h = lane >> 5;      // half id: edge parity this lane serves
    const int q = lane & 31;      // sublane: owns dims [4q, 4q+4)

    int2 my_e = eb[lane];         // lane i owns edge i (SLOT_CAP >= 64)
    int  myc  = my_e.x;
    const float* mybase = (myc < U) ? (user_emb + (size_t)myc * EMB_D)
                                    : (item_emb + (size_t)(myc - U) * EMB_D);
    unsigned long long mba = (unsigned long long)mybase;
    int   b_lo = (int)(unsigned)mba;
    int   b_hi = (int)(mba >> 32);
    float myv  = __int_as_float(my_e.y);

    float4 acc0 = {0.f, 0.f, 0.f, 0.f};
    float4 acc1 = {0.f, 0.f, 0.f, 0.f};

    const int n0 = dc < 64 ? dc : 64;
    for (int j = 0; j < n0; j += 16) {
        const float* p[8];
        float vv[8];
#pragma unroll
        for (int k = 0; k < 8; ++k) {           // register-only shfl broadcast
            int jj   = j + 2 * k + h;
            int srcl = (jj < n0) ? jj : 0;      // lane 0 always valid (n0 > 0 here)
            int lo = __shfl(b_lo, srcl);
            int hi = __shfl(b_hi, srcl);
            float vx = __shfl(myv, srcl);
            vv[k] = (jj < n0) ? vx : 0.f;       // mask tail contribution
            p[k]  = (const float*)((((unsigned long long)(unsigned)hi) << 32)
                                   | (unsigned)lo);
        }
        float4 x[8];
#pragma unroll
        for (int k = 0; k < 8; ++k)             // 8 independent 512B-row loads
            x[k] = *(const float4*)(p[k] + q * 4);
        __builtin_amdgcn_sched_barrier(0);      // keep loads clustered
#pragma unroll
        for (int k = 0; k < 8; ++k)
            fma4((k & 1) ? acc1 : acc0, vv[k], x[k]);
    }

    float4 r;
    r.x = acc0.x + acc1.x;
    r.y = acc0.y + acc1.y;
    r.z = acc0.z + acc1.z;
    r.w = acc0.w + acc1.w;
    // combine the two halves: each half held edges of its parity
    r.x += __shfl_xor(r.x, 32);
    r.y += __shfl_xor(r.y, 32);
    r.z += __shfl_xor(r.z, 32);
    r.w += __shfl_xor(r.w, 32);

    if (h == 0) {
        for (int j = 64; j < dc; ++j) {         // rare tail: deg in (64, SLOT_CAP]
            int2 ed = eb[j];
            int c = ed.x;
            float v = __int_as_float(ed.y);
            const float* src = (c < U) ? (user_emb + (size_t)c * EMB_D)
                                       : (item_emb + (size_t)(c - U) * EMB_D);
            float4 xx = *(const float4*)(src + q * 4);
            fma4(r, v, xx);
        }
        // fold in layer-0: f = e0[node] + e1
        int node = slot2node[wid];              // 0 for unclaimed slots (harmless)
        const float* e0row = (node < U) ? (user_emb + (size_t)node * EMB_D)
                                        : (item_emb + (size_t)(node - U) * EMB_D);
        float4 e0v = *(const float4*)(e0row + q * 4);
        r.x += e0v.x; r.y += e0v.y; r.z += e0v.z; r.w += e0v.w;

        float4* dst = (float4*)(comp + (size_t)wid * EMB_D) + q;
        if (ovf) {  // overflow part already added atomically into comp
            float4 o = *dst;
            r.x += o.x; r.y += o.y; r.z += o.z; r.w += o.w;
        }
        *dst = r;
    }
}

// ---------- Pass 4 (tier A): dot of two dense comp rows. One wave per pair. ----------
__global__ void final_kernel(const int* __restrict__ user_idx,
                             const int* __restrict__ item_idx,
                             const int* __restrict__ node_map,
                             const float* __restrict__ comp,
                             float* __restrict__ out, int B, int U) {
    int wid  = (blockIdx.x * blockDim.x + threadIdx.x) >> 6;
    int lane = threadIdx.x & 63;
    if (wid >= B) return;
    int su = node_map[user_idx[wid]] - 1;
    int si = node_map[U + item_idx[wid]] - 1;
    float2 fu = *(const float2*)(comp + (size_t)su * EMB_D + lane * 2);
    float2 fi = *(const float2*)(comp + (size_t)si * EMB_D + lane * 2);
    float p = fu.x * fi.x + fu.y * fi.y;
#pragma unroll
    for (int off = 32; off; off >>= 1) p += __shfl_down(p, off);
    if (lane == 0) out[wid] = 0.25f * p;
}

// ---------- Tier-C fallback: scatter + raw final (comp holds e1 only). ----------
__global__ void scatter_kernel(const float* __restrict__ user_emb,
                               const float* __restrict__ item_emb,
                               const float* __restrict__ vals,
                               const int* __restrict__ rows,
                               const int* __restrict__ cols,
                               const int* __restrict__ node_map,
                               float* __restrict__ comp,
                               int nnz, int U) {
    int e = blockIdx.x * blockDim.x + threadIdx.x;
    int lane = threadIdx.x & 63;
    int s = 0; int c = 0; float v = 0.f;
    if (e < nnz) {
        int r = rows[e];
        s = node_map[r];
        if (s != 0) { c = cols[e]; v = vals[e]; }
    }
    unsigned long long mask = __ballot(s != 0);
    while (mask) {
        int j = __ffsll((long long)mask) - 1;
        mask &= mask - 1;
        int   cj    = __shfl(c, j);
        float vj    = __shfl(v, j);
        int   slotj = __shfl(s, j) - 1;
        const float* src = (cj < U) ? (user_emb + (size_t)cj * EMB_D)
                                    : (item_emb + (size_t)(cj - U) * EMB_D);
        float2 xx = *(const float2*)(src + lane * 2);
        float* dst = comp + (size_t)slotj * EMB_D + lane * 2;
        atomicAdd(dst,     xx.x * vj);
        atomicAdd(dst + 1, xx.y * vj);
    }
}

__global__ void final_raw_kernel(const float* __restrict__ user_emb,
                                 const float* __restrict__ item_emb,
                                 const int* __restrict__ user_idx,
                                 const int* __restrict__ item_idx,
                                 const int* __restrict__ node_map,
                                 const float* __restrict__ comp,
                                 float* __restrict__ out, int B, int U) {
    int wid  = (blockIdx.x * blockDim.x + threadIdx.x) >> 6;
    int lane = threadIdx.x & 63;
    if (wid >= B) return;
    int un  = user_idx[wid];
    int inn = item_idx[wid];
    int su  = node_map[un] - 1;
    int si  = node_map[U + inn] - 1;
    float2 eu = *(const float2*)(user_emb + (size_t)un * EMB_D + lane * 2);
    float2 ei = *(const float2*)(item_emb + (size_t)inn * EMB_D + lane * 2);
    float2 cu = *(const float2*)(comp + (size_t)su * EMB_D + lane * 2);
    float2 ci = *(const float2*)(comp + (size_t)si * EMB_D + lane * 2);
    float p = (eu.x + cu.x) * (ei.x + ci.x) + (eu.y + cu.y) * (ei.y + ci.y);
#pragma unroll
    for (int off = 32; off; off >>= 1) p += __shfl_down(p, off);
    if (lane == 0) out[wid] = 0.25f * p;
}

extern "C" void kernel_launch(void* const* d_in, const int* in_sizes, int n_in,
                              void* d_out, int out_size, void* d_ws, size_t ws_size,
                              hipStream_t stream) {
    const float* user_emb = (const float*)d_in[0];
    const float* item_emb = (const float*)d_in[1];
    const float* adj_vals = (const float*)d_in[2];
    const int*   adj_rows = (const int*)d_in[3];
    const int*   adj_cols = (const int*)d_in[4];
    const int*   user_idx = (const int*)d_in[5];
    const int*   item_idx = (const int*)d_in[6];
    float* out = (float*)d_out;

    int U   = in_sizes[0] / EMB_D;
    int I   = in_sizes[1] / EMB_D;
    int N   = U + I;
    int nnz = in_sizes[2];
    int B   = in_sizes[5];
    int S   = 2 * B;                       // slot count
    int nwords = (N + 31) / 32;            // bitmap words

    // Workspace: [comp S*D f32][map N i32][deg S i32][bitmap][slot2node S i32][edge_buf]
    size_t comp_bytes = (size_t)S * EMB_D * sizeof(float);
    size_t map_bytes  = ((size_t)N * sizeof(int) + 15) & ~(size_t)15;
    size_t deg_bytes  = (((size_t)S) * sizeof(int) + 15) & ~(size_t)15;
    size_t bm_bytes   = (((size_t)nwords) * sizeof(unsigned) + 15) & ~(size_t)15;
    size_t s2n_bytes  = (((size_t)S) * sizeof(int) + 15) & ~(size_t)15;
    size_t edge_bytes = (size_t)S * SLOT_CAP * sizeof(int2);
    size_t zero_bytes = comp_bytes + map_bytes + deg_bytes + bm_bytes + s2n_bytes;
    size_t fixed      = zero_bytes + edge_bytes;

    float*    comp      = (float*)d_ws;
    int*      node_map  = (int*)((char*)d_ws + comp_bytes);
    int*      deg       = (int*)((char*)d_ws + comp_bytes + map_bytes);
    unsigned* bitmap    = (unsigned*)((char*)d_ws + comp_bytes + map_bytes + deg_bytes);
    int*      slot2node = (int*)((char*)d_ws + comp_bytes + map_bytes + deg_bytes + bm_bytes);
    int2*     edge_buf  = (int2*)((char*)d_ws + zero_bytes);

    size_t lds_bytes = (size_t)nwords * sizeof(unsigned);

    if (ws_size >= fixed && lds_bytes <= 64 * 1024) {
        // comp must be zero before fill (overflow fallback atomics land there).
        hipMemsetAsync(d_ws, 0, zero_bytes, stream);
        claim_kernel<<<(S + 255) / 256, 256, 0, stream>>>(
            user_idx, item_idx, node_map, slot2node, bitmap, B, U);
        fill3_kernel<<<1024, FILL_THREADS, lds_bytes, stream>>>(
            user_emb, item_emb, adj_vals, adj_rows, adj_cols, node_map,
            bitmap, nwords, deg, edge_buf, comp, (long long)nnz, U);
        gather_kernel<<<(S * 64 + 255) / 256, 256, 0, stream>>>(
            user_emb, item_emb, edge_buf, deg, slot2node, comp, S, U);
        final_kernel<<<(B * 64 + 255) / 256, 256, 0, stream>>>(
            user_idx, item_idx, node_map, comp, out, B, U);
    } else {
        hipMemsetAsync(d_ws, 0, comp_bytes + map_bytes, stream);
        claim_kernel<<<(S + 255) / 256, 256, 0, stream>>>(
            user_idx, item_idx, node_map, slot2node, bitmap, B, U);
        scatter_kernel<<<(nnz + 255) / 256, 256, 0, stream>>>(
            user_emb, item_emb, adj_vals, adj_rows, adj_cols, node_map,
            comp, nnz, U);
        final_raw_kernel<<<(B * 64 + 255) / 256, 256, 0, stream>>>(
            user_emb, item_emb, user_idx, item_idx, node_map, comp, out, B, U);
    }
}